// Round 1
// baseline (630.497 us; speedup 1.0000x reference)
//
#include <hip/hip_runtime.h>
#include <math.h>

#define B_   8
#define C_   256
#define CI_  128
#define N_   1024
#define HW_  32
#define CO_  256

// ---------------------------------------------------------------------------
// K1: fused strided-gather + qkv projection GEMM.
// qkv[b][o][n] = sum_c Wsel[o][c] * x[b][c][4*(n/32)][4*(n%32)], o in [0,384)
// 64x64 tile, K=256 in chunks of 64, 4x4 per thread.
__global__ __launch_bounds__(256) void proj_kernel(
    const float* __restrict__ x, const float* __restrict__ Wq,
    const float* __restrict__ Wk, const float* __restrict__ Wv,
    float* __restrict__ qkv)
{
    __shared__ float Wl[64][68];   // [k][o], pad 68 keeps float4 16B-aligned
    __shared__ float Xl[64][68];   // [k][n]
    const int n0 = blockIdx.x * 64;
    const int o0 = blockIdx.y * 64;
    const int b  = blockIdx.z;
    const int tid = threadIdx.x;
    const int tx = tid & 15, ty = tid >> 4;

    const float* Wbase = (o0 < 128) ? (Wq + o0 * C_)
                        : (o0 < 256) ? (Wk + (o0 - 128) * C_)
                        : (Wv + (o0 - 256) * C_);

    float acc[4][4] = {};

    for (int k0 = 0; k0 < C_; k0 += 64) {
        // Stage W tile: float4 over k (contiguous in global), scatter into [k][o]
        for (int idx = tid; idx < 1024; idx += 256) {
            int kk = (idx & 15) * 4;
            int oo = idx >> 4;
            float4 w4 = *(const float4*)&Wbase[oo * C_ + k0 + kk];
            Wl[kk + 0][oo] = w4.x; Wl[kk + 1][oo] = w4.y;
            Wl[kk + 2][oo] = w4.z; Wl[kk + 3][oo] = w4.w;
        }
        // Stage X tile (strided gather, scalar loads)
        for (int idx = tid; idx < 4096; idx += 256) {
            int nn = idx & 63, kk = idx >> 6;
            int n = n0 + nn;
            Xl[kk][nn] = x[((b * C_ + k0 + kk) * 128 + (n >> 5) * 4) * 128 + (n & 31) * 4];
        }
        __syncthreads();
        #pragma unroll 8
        for (int k = 0; k < 64; ++k) {
            float4 a4 = *(const float4*)&Wl[k][tx * 4];
            float4 b4 = *(const float4*)&Xl[k][ty * 4];
            float av[4] = {a4.x, a4.y, a4.z, a4.w};
            float bv[4] = {b4.x, b4.y, b4.z, b4.w};
            #pragma unroll
            for (int j = 0; j < 4; ++j)
                #pragma unroll
                for (int i = 0; i < 4; ++i)
                    acc[j][i] += av[j] * bv[i];
        }
        __syncthreads();
    }
    #pragma unroll
    for (int j = 0; j < 4; ++j) {
        int o = o0 + tx * 4 + j;
        float4 r = make_float4(acc[j][0], acc[j][1], acc[j][2], acc[j][3]);
        *(float4*)&qkv[(size_t)(b * 384 + o) * N_ + n0 + ty * 4] = r;
    }
}

// ---------------------------------------------------------------------------
// K2: scores[b][n][m] = sum_c q[b][c][n] * k[b][c][m]   (K=128)
__global__ __launch_bounds__(256) void scores_kernel(
    const float* __restrict__ qkv, float* __restrict__ gate)
{
    __shared__ float Ql[64][68];   // [c][n]
    __shared__ float Kl[64][68];   // [c][m]
    const int m0 = blockIdx.x * 64;
    const int n0 = blockIdx.y * 64;
    const int b  = blockIdx.z;
    const int tid = threadIdx.x;
    const int tx = tid & 15, ty = tid >> 4;

    const float* qb = qkv + (size_t)b * 384 * N_;
    const float* kb = qb + 128 * N_;

    float acc[4][4] = {};

    for (int c0 = 0; c0 < 128; c0 += 64) {
        for (int idx = tid; idx < 1024; idx += 256) {
            int nn = (idx & 15) * 4;
            int kk = idx >> 4;
            *(float4*)&Ql[kk][nn] = *(const float4*)&qb[(c0 + kk) * N_ + n0 + nn];
            *(float4*)&Kl[kk][nn] = *(const float4*)&kb[(c0 + kk) * N_ + m0 + nn];
        }
        __syncthreads();
        #pragma unroll 8
        for (int k = 0; k < 64; ++k) {
            float4 q4 = *(const float4*)&Ql[k][ty * 4];
            float4 k4 = *(const float4*)&Kl[k][tx * 4];
            float av[4] = {q4.x, q4.y, q4.z, q4.w};
            float bv[4] = {k4.x, k4.y, k4.z, k4.w};
            #pragma unroll
            for (int i = 0; i < 4; ++i)
                #pragma unroll
                for (int j = 0; j < 4; ++j)
                    acc[i][j] += av[i] * bv[j];
        }
        __syncthreads();
    }
    #pragma unroll
    for (int i = 0; i < 4; ++i) {
        float4 r = make_float4(acc[i][0], acc[i][1], acc[i][2], acc[i][3]);
        *(float4*)&gate[((size_t)(b * N_) + n0 + ty * 4 + i) * N_ + m0 + tx * 4] = r;
    }
}

// ---------------------------------------------------------------------------
// K3: in-place row softmax over gate rows (1024 elements per row)
__global__ __launch_bounds__(256) void softmax_kernel(float* __restrict__ gate)
{
    const int n = blockIdx.x, b = blockIdx.y;
    float* row = gate + ((size_t)(b * N_ + n)) * N_;
    const int tid = threadIdx.x;
    const int wid = tid >> 6, lane = tid & 63;
    __shared__ float redm[4];
    __shared__ float reds[4];

    float4 v = ((const float4*)row)[tid];
    float m = fmaxf(fmaxf(v.x, v.y), fmaxf(v.z, v.w));
    #pragma unroll
    for (int off = 32; off; off >>= 1) m = fmaxf(m, __shfl_xor(m, off, 64));
    if (lane == 0) redm[wid] = m;
    __syncthreads();
    m = fmaxf(fmaxf(redm[0], redm[1]), fmaxf(redm[2], redm[3]));

    float4 e;
    e.x = __expf(v.x - m); e.y = __expf(v.y - m);
    e.z = __expf(v.z - m); e.w = __expf(v.w - m);
    float s = e.x + e.y + e.z + e.w;
    #pragma unroll
    for (int off = 32; off; off >>= 1) s += __shfl_xor(s, off, 64);
    if (lane == 0) reds[wid] = s;
    __syncthreads();
    s = reds[0] + reds[1] + reds[2] + reds[3];
    float inv = 1.0f / s;
    e.x *= inv; e.y *= inv; e.z *= inv; e.w *= inv;
    ((float4*)row)[tid] = e;
}

// ---------------------------------------------------------------------------
// K4: gv[b][c][n] = sum_m gate[b][n][m] * v[b][c][m]  (K=1024, split in 2, atomics)
__global__ __launch_bounds__(256) void gv_kernel(
    const float* __restrict__ qkv, const float* __restrict__ gate,
    float* __restrict__ gv)
{
    __shared__ float Gl[64][68];   // [m][n]
    __shared__ float Vl[64][68];   // [m][c]
    const int n0 = blockIdx.x * 64;
    const int c0 = blockIdx.y * 64;
    const int z  = blockIdx.z;
    const int b  = z >> 1, ks = z & 1;
    const int tid = threadIdx.x;
    const int tx = tid & 15, ty = tid >> 4;

    const float* vb = qkv + ((size_t)b * 384 + 256) * N_;
    const float* gb = gate + (size_t)b * N_ * N_;

    float acc[4][4] = {};

    for (int kc = 0; kc < 8; ++kc) {
        int m0 = ks * 512 + kc * 64;
        for (int idx = tid; idx < 1024; idx += 256) {
            int kk = (idx & 15) * 4;
            int nn = idx >> 4;
            float4 g4 = *(const float4*)&gb[(size_t)(n0 + nn) * N_ + m0 + kk];
            Gl[kk + 0][nn] = g4.x; Gl[kk + 1][nn] = g4.y;
            Gl[kk + 2][nn] = g4.z; Gl[kk + 3][nn] = g4.w;
            float4 v4 = *(const float4*)&vb[(c0 + nn) * N_ + m0 + kk];
            Vl[kk + 0][nn] = v4.x; Vl[kk + 1][nn] = v4.y;
            Vl[kk + 2][nn] = v4.z; Vl[kk + 3][nn] = v4.w;
        }
        __syncthreads();
        #pragma unroll 8
        for (int k = 0; k < 64; ++k) {
            float4 g4 = *(const float4*)&Gl[k][ty * 4];
            float4 v4 = *(const float4*)&Vl[k][tx * 4];
            float av[4] = {g4.x, g4.y, g4.z, g4.w};
            float bv[4] = {v4.x, v4.y, v4.z, v4.w};
            #pragma unroll
            for (int i = 0; i < 4; ++i)
                #pragma unroll
                for (int j = 0; j < 4; ++j)
                    acc[i][j] += av[i] * bv[j];
        }
        __syncthreads();
    }
    #pragma unroll
    for (int j = 0; j < 4; ++j)
        #pragma unroll
        for (int i = 0; i < 4; ++i)
            atomicAdd(&gv[(size_t)(b * CI_ + c0 + tx * 4 + j) * N_ + n0 + ty * 4 + i],
                      acc[i][j]);
}

// ---------------------------------------------------------------------------
// K5: meanb[b][c] = mean over 1024 pixels of gv[b][c][:]
__global__ __launch_bounds__(256) void mean_kernel(
    const float* __restrict__ gv, float* __restrict__ meanb)
{
    const int i = blockIdx.x, b = blockIdx.y;
    const int tid = threadIdx.x;
    const int wid = tid >> 6, lane = tid & 63;
    __shared__ float red[4];
    const float* base = gv + (size_t)(b * CI_ + i) * N_;
    float4 v = ((const float4*)base)[tid];
    float s = v.x + v.y + v.z + v.w;
    #pragma unroll
    for (int off = 32; off; off >>= 1) s += __shfl_xor(s, off, 64);
    if (lane == 0) red[wid] = s;
    __syncthreads();
    if (tid == 0)
        meanb[b * CI_ + i] = (red[0] + red[1] + red[2] + red[3]) * (1.0f / 1024.0f);
}

// ---------------------------------------------------------------------------
// K6: conv1d over channel dim (pad 1) + sigmoid -> ca
__global__ __launch_bounds__(1024) void ca_kernel(
    const float* __restrict__ meanb, const float* __restrict__ w1d,
    float* __restrict__ ca)
{
    const int t = threadIdx.x;        // 0..1023 = b*128 + i
    const int i = t & 127;
    float left  = (i > 0)   ? meanb[t - 1] : 0.0f;
    float mid   = meanb[t];
    float right = (i < 127) ? meanb[t + 1] : 0.0f;
    float val = w1d[0] * left + w1d[1] * mid + w1d[2] * right;
    ca[t] = 1.0f / (1.0f + __expf(-val));
}

// ---------------------------------------------------------------------------
// K7: out[b][o][h][w] = sum_{i,dy,dx} Wc[o][i][dy][dx] * (gv[b][i][h+dy-1][w+dx-1]*ca[b][i])
// Block: 8 out-channels x half-image (16 rows). 8-channel LDS halo tiles.
__global__ __launch_bounds__(256) void conv_kernel(
    const float* __restrict__ gv, const float* __restrict__ ca,
    const float* __restrict__ Wc, float* __restrict__ out)
{
    __shared__ float tile[8][18][35];
    const int o0   = blockIdx.x * 8;
    const int half = blockIdx.y;
    const int b    = blockIdx.z;
    const int tid  = threadIdx.x;
    const int c    = tid & 31;        // output col
    const int rloc = tid >> 5;        // 0..7
    const int rowbase = half * 16 - 1;

    float acc[2][8] = {};

    for (int i0 = 0; i0 < CI_; i0 += 8) {
        // stage 8 channels of padded 18x34 halo tile
        for (int idx = tid; idx < 8 * 18 * 34; idx += 256) {
            int ci  = idx / 612;
            int rem = idx - ci * 612;
            int rr  = rem / 34;
            int cc  = rem - rr * 34;
            int gr  = rowbase + rr;
            int gc  = cc - 1;
            float v = 0.0f;
            if ((unsigned)gr < 32u && (unsigned)gc < 32u)
                v = gv[(size_t)(b * CI_ + i0 + ci) * N_ + gr * 32 + gc];
            tile[ci][rr][cc] = v;
        }
        __syncthreads();

        #pragma unroll
        for (int ci = 0; ci < 8; ++ci) {
            float cav = ca[b * CI_ + i0 + ci];
            // 9 taps for both pixels (rows rloc and rloc+8 of the half)
            float v0[3][3], v1[3][3];
            #pragma unroll
            for (int dy = 0; dy < 3; ++dy)
                #pragma unroll
                for (int dx = 0; dx < 3; ++dx) {
                    v0[dy][dx] = tile[ci][rloc + dy][c + dx] * cav;
                    v1[dy][dx] = tile[ci][rloc + 8 + dy][c + dx] * cav;
                }
            #pragma unroll
            for (int oo = 0; oo < 8; ++oo) {
                const float* wp = Wc + (size_t)((o0 + oo) * CI_ + i0 + ci) * 9;
                float s0 = 0.0f, s1 = 0.0f;
                #pragma unroll
                for (int dy = 0; dy < 3; ++dy)
                    #pragma unroll
                    for (int dx = 0; dx < 3; ++dx) {
                        float w = wp[dy * 3 + dx];
                        s0 += w * v0[dy][dx];
                        s1 += w * v1[dy][dx];
                    }
                acc[0][oo] += s0;
                acc[1][oo] += s1;
            }
        }
        __syncthreads();
    }

    #pragma unroll
    for (int px = 0; px < 2; ++px) {
        int h = half * 16 + px * 8 + rloc;
        #pragma unroll
        for (int oo = 0; oo < 8; ++oo)
            out[(size_t)(b * CO_ + o0 + oo) * N_ + h * 32 + c] = acc[px][oo];
    }
}

// ---------------------------------------------------------------------------
extern "C" void kernel_launch(void* const* d_in, const int* in_sizes, int n_in,
                              void* d_out, int out_size, void* d_ws, size_t ws_size,
                              hipStream_t stream) {
    const float* x   = (const float*)d_in[0];
    const float* Wq  = (const float*)d_in[1];
    const float* Wk  = (const float*)d_in[2];
    const float* Wv  = (const float*)d_in[3];
    const float* w1d = (const float*)d_in[4];
    const float* Wc  = (const float*)d_in[5];

    float* out  = (float*)d_out;                  // 8*256*32*32 = 2097152
    float* gate = out + 2097152;                  // 8*1024*1024 = 8388608
    float* ca   = gate + 8388608;                 // 8*128 = 1024

    float* qkv   = (float*)d_ws;                  // 8*384*1024 = 3145728 floats
    float* gv    = qkv + 3145728;                 // 8*128*1024 = 1048576 floats
    float* meanb = gv + 1048576;                  // 1024 floats

    proj_kernel<<<dim3(16, 6, 8), 256, 0, stream>>>(x, Wq, Wk, Wv, qkv);
    scores_kernel<<<dim3(16, 16, 8), 256, 0, stream>>>(qkv, gate);
    softmax_kernel<<<dim3(1024, 8), 256, 0, stream>>>(gate);
    hipMemsetAsync(gv, 0, (size_t)1048576 * sizeof(float), stream);
    gv_kernel<<<dim3(16, 2, 16), 256, 0, stream>>>(qkv, gate, gv);
    mean_kernel<<<dim3(128, 8), 256, 0, stream>>>(gv, meanb);
    ca_kernel<<<1, 1024, 0, stream>>>(meanb, w1d, ca);
    conv_kernel<<<dim3(32, 2, 8), 256, 0, stream>>>(gv, ca, Wc, out);
}

// Round 2
// 366.158 us; speedup vs baseline: 1.7219x; 1.7219x over previous
//
#include <hip/hip_runtime.h>
#include <math.h>

#define B_   8
#define C_   256
#define CI_  128
#define N_   1024
#define HW_  32
#define CO_  256

typedef __bf16 v8bf __attribute__((ext_vector_type(8)));
typedef float  f32x4 __attribute__((ext_vector_type(4)));

__device__ __forceinline__ unsigned short f2bf_rne(float f) {
    unsigned int u = __float_as_uint(f);
    unsigned int r = u + 0x7FFF + ((u >> 16) & 1);
    return (unsigned short)(r >> 16);
}
__device__ __forceinline__ float bf2f(unsigned short h) {
    return __uint_as_float(((unsigned int)h) << 16);
}

// ---------------------------------------------------------------------------
// K1: fused strided-gather + qkv projection GEMM (fp32, unchanged)
__global__ __launch_bounds__(256) void proj_kernel(
    const float* __restrict__ x, const float* __restrict__ Wq,
    const float* __restrict__ Wk, const float* __restrict__ Wv,
    float* __restrict__ qkv)
{
    __shared__ float Wl[64][68];
    __shared__ float Xl[64][68];
    const int n0 = blockIdx.x * 64;
    const int o0 = blockIdx.y * 64;
    const int b  = blockIdx.z;
    const int tid = threadIdx.x;
    const int tx = tid & 15, ty = tid >> 4;

    const float* Wbase = (o0 < 128) ? (Wq + o0 * C_)
                        : (o0 < 256) ? (Wk + (o0 - 128) * C_)
                        : (Wv + (o0 - 256) * C_);

    float acc[4][4] = {};

    for (int k0 = 0; k0 < C_; k0 += 64) {
        for (int idx = tid; idx < 1024; idx += 256) {
            int kk = (idx & 15) * 4;
            int oo = idx >> 4;
            float4 w4 = *(const float4*)&Wbase[oo * C_ + k0 + kk];
            Wl[kk + 0][oo] = w4.x; Wl[kk + 1][oo] = w4.y;
            Wl[kk + 2][oo] = w4.z; Wl[kk + 3][oo] = w4.w;
        }
        for (int idx = tid; idx < 4096; idx += 256) {
            int nn = idx & 63, kk = idx >> 6;
            int n = n0 + nn;
            Xl[kk][nn] = x[((b * C_ + k0 + kk) * 128 + (n >> 5) * 4) * 128 + (n & 31) * 4];
        }
        __syncthreads();
        #pragma unroll 8
        for (int k = 0; k < 64; ++k) {
            float4 a4 = *(const float4*)&Wl[k][tx * 4];
            float4 b4 = *(const float4*)&Xl[k][ty * 4];
            float av[4] = {a4.x, a4.y, a4.z, a4.w};
            float bv[4] = {b4.x, b4.y, b4.z, b4.w};
            #pragma unroll
            for (int j = 0; j < 4; ++j)
                #pragma unroll
                for (int i = 0; i < 4; ++i)
                    acc[j][i] += av[j] * bv[i];
        }
        __syncthreads();
    }
    #pragma unroll
    for (int j = 0; j < 4; ++j) {
        int o = o0 + tx * 4 + j;
        float4 r = make_float4(acc[j][0], acc[j][1], acc[j][2], acc[j][3]);
        *(float4*)&qkv[(size_t)(b * 384 + o) * N_ + n0 + ty * 4] = r;
    }
}

// ---------------------------------------------------------------------------
// K2: scores (fp32, unchanged)
__global__ __launch_bounds__(256) void scores_kernel(
    const float* __restrict__ qkv, float* __restrict__ gate)
{
    __shared__ float Ql[64][68];
    __shared__ float Kl[64][68];
    const int m0 = blockIdx.x * 64;
    const int n0 = blockIdx.y * 64;
    const int b  = blockIdx.z;
    const int tid = threadIdx.x;
    const int tx = tid & 15, ty = tid >> 4;

    const float* qb = qkv + (size_t)b * 384 * N_;
    const float* kb = qb + 128 * N_;

    float acc[4][4] = {};

    for (int c0 = 0; c0 < 128; c0 += 64) {
        for (int idx = tid; idx < 1024; idx += 256) {
            int nn = (idx & 15) * 4;
            int kk = idx >> 4;
            *(float4*)&Ql[kk][nn] = *(const float4*)&qb[(c0 + kk) * N_ + n0 + nn];
            *(float4*)&Kl[kk][nn] = *(const float4*)&kb[(c0 + kk) * N_ + m0 + nn];
        }
        __syncthreads();
        #pragma unroll 8
        for (int k = 0; k < 64; ++k) {
            float4 q4 = *(const float4*)&Ql[k][ty * 4];
            float4 k4 = *(const float4*)&Kl[k][tx * 4];
            float av[4] = {q4.x, q4.y, q4.z, q4.w};
            float bv[4] = {k4.x, k4.y, k4.z, k4.w};
            #pragma unroll
            for (int i = 0; i < 4; ++i)
                #pragma unroll
                for (int j = 0; j < 4; ++j)
                    acc[i][j] += av[i] * bv[j];
        }
        __syncthreads();
    }
    #pragma unroll
    for (int i = 0; i < 4; ++i) {
        float4 r = make_float4(acc[i][0], acc[i][1], acc[i][2], acc[i][3]);
        *(float4*)&gate[((size_t)(b * N_) + n0 + ty * 4 + i) * N_ + m0 + tx * 4] = r;
    }
}

// ---------------------------------------------------------------------------
// K3: softmax (unchanged)
__global__ __launch_bounds__(256) void softmax_kernel(float* __restrict__ gate)
{
    const int n = blockIdx.x, b = blockIdx.y;
    float* row = gate + ((size_t)(b * N_ + n)) * N_;
    const int tid = threadIdx.x;
    const int wid = tid >> 6, lane = tid & 63;
    __shared__ float redm[4];
    __shared__ float reds[4];

    float4 v = ((const float4*)row)[tid];
    float m = fmaxf(fmaxf(v.x, v.y), fmaxf(v.z, v.w));
    #pragma unroll
    for (int off = 32; off; off >>= 1) m = fmaxf(m, __shfl_xor(m, off, 64));
    if (lane == 0) redm[wid] = m;
    __syncthreads();
    m = fmaxf(fmaxf(redm[0], redm[1]), fmaxf(redm[2], redm[3]));

    float4 e;
    e.x = __expf(v.x - m); e.y = __expf(v.y - m);
    e.z = __expf(v.z - m); e.w = __expf(v.w - m);
    float s = e.x + e.y + e.z + e.w;
    #pragma unroll
    for (int off = 32; off; off >>= 1) s += __shfl_xor(s, off, 64);
    if (lane == 0) reds[wid] = s;
    __syncthreads();
    s = reds[0] + reds[1] + reds[2] + reds[3];
    float inv = 1.0f / s;
    e.x *= inv; e.y *= inv; e.z *= inv; e.w *= inv;
    ((float4*)row)[tid] = e;
}

// ---------------------------------------------------------------------------
// K4: gv GEMM (fp32, unchanged)
__global__ __launch_bounds__(256) void gv_kernel(
    const float* __restrict__ qkv, const float* __restrict__ gate,
    float* __restrict__ gv)
{
    __shared__ float Gl[64][68];
    __shared__ float Vl[64][68];
    const int n0 = blockIdx.x * 64;
    const int c0 = blockIdx.y * 64;
    const int z  = blockIdx.z;
    const int b  = z >> 1, ks = z & 1;
    const int tid = threadIdx.x;
    const int tx = tid & 15, ty = tid >> 4;

    const float* vb = qkv + ((size_t)b * 384 + 256) * N_;
    const float* gb = gate + (size_t)b * N_ * N_;

    float acc[4][4] = {};

    for (int kc = 0; kc < 8; ++kc) {
        int m0 = ks * 512 + kc * 64;
        for (int idx = tid; idx < 1024; idx += 256) {
            int kk = (idx & 15) * 4;
            int nn = idx >> 4;
            float4 g4 = *(const float4*)&gb[(size_t)(n0 + nn) * N_ + m0 + kk];
            Gl[kk + 0][nn] = g4.x; Gl[kk + 1][nn] = g4.y;
            Gl[kk + 2][nn] = g4.z; Gl[kk + 3][nn] = g4.w;
            float4 v4 = *(const float4*)&vb[(c0 + nn) * N_ + m0 + kk];
            Vl[kk + 0][nn] = v4.x; Vl[kk + 1][nn] = v4.y;
            Vl[kk + 2][nn] = v4.z; Vl[kk + 3][nn] = v4.w;
        }
        __syncthreads();
        #pragma unroll 8
        for (int k = 0; k < 64; ++k) {
            float4 g4 = *(const float4*)&Gl[k][ty * 4];
            float4 v4 = *(const float4*)&Vl[k][tx * 4];
            float av[4] = {g4.x, g4.y, g4.z, g4.w};
            float bv[4] = {v4.x, v4.y, v4.z, v4.w};
            #pragma unroll
            for (int i = 0; i < 4; ++i)
                #pragma unroll
                for (int j = 0; j < 4; ++j)
                    acc[i][j] += av[i] * bv[j];
        }
        __syncthreads();
    }
    #pragma unroll
    for (int j = 0; j < 4; ++j)
        #pragma unroll
        for (int i = 0; i < 4; ++i)
            atomicAdd(&gv[(size_t)(b * CI_ + c0 + tx * 4 + j) * N_ + n0 + ty * 4 + i],
                      acc[i][j]);
}

// ---------------------------------------------------------------------------
// K5: mean (unchanged)
__global__ __launch_bounds__(256) void mean_kernel(
    const float* __restrict__ gv, float* __restrict__ meanb)
{
    const int i = blockIdx.x, b = blockIdx.y;
    const int tid = threadIdx.x;
    const int wid = tid >> 6, lane = tid & 63;
    __shared__ float red[4];
    const float* base = gv + (size_t)(b * CI_ + i) * N_;
    float4 v = ((const float4*)base)[tid];
    float s = v.x + v.y + v.z + v.w;
    #pragma unroll
    for (int off = 32; off; off >>= 1) s += __shfl_xor(s, off, 64);
    if (lane == 0) red[wid] = s;
    __syncthreads();
    if (tid == 0)
        meanb[b * CI_ + i] = (red[0] + red[1] + red[2] + red[3]) * (1.0f / 1024.0f);
}

// ---------------------------------------------------------------------------
// K6: conv1d + sigmoid (unchanged)
__global__ __launch_bounds__(1024) void ca_kernel(
    const float* __restrict__ meanb, const float* __restrict__ w1d,
    float* __restrict__ ca)
{
    const int t = threadIdx.x;
    const int i = t & 127;
    float left  = (i > 0)   ? meanb[t - 1] : 0.0f;
    float mid   = meanb[t];
    float right = (i < 127) ? meanb[t + 1] : 0.0f;
    float val = w1d[0] * left + w1d[1] * mid + w1d[2] * right;
    ca[t] = 1.0f / (1.0f + __expf(-val));
}

// ---------------------------------------------------------------------------
// K7a: split Wc into bf16 hi/lo planes, layout [o][tap][ci] (k' = tap*128+ci)
__global__ __launch_bounds__(256) void prep_w_kernel(
    const float* __restrict__ Wc, unsigned short* __restrict__ Whi,
    unsigned short* __restrict__ Wlo)
{
    int idx = blockIdx.x * 256 + threadIdx.x;   // 256*128*9 = 294912
    int o = idx / 1152;
    int r = idx - o * 1152;
    int ci = r / 9;
    int tap = r - ci * 9;
    float v = Wc[idx];
    unsigned short h = f2bf_rne(v);
    unsigned short l = f2bf_rne(v - bf2f(h));
    int didx = o * 1152 + tap * 128 + ci;
    Whi[didx] = h; Wlo[didx] = l;
}

// ---------------------------------------------------------------------------
// K7b: MFMA conv. out[b][o][h][w] = sum_{ci,dy,dx} Wc[o][ci][dy][dx]*gv[b][ci][h+dy-1][w+dx-1]*ca[b][ci]
// Split-bf16 (hi/lo) on both operands: acc += Ah*Bh + Ah*Bl + Al*Bh  (~fp32 accuracy).
// Block: 64 out-ch x 2 image rows (64 px). 4 waves = 2(o) x 2(row).
// LDS: B planes = gv*ca halo tile [136 pxslot][64 ci] bf16 hi+lo (per ci-half),
//      A planes = W [64 o][64 ci] hi+lo per tap. XOR chunk swizzle -> 2-way max.
#define BHI 0
#define BLO 17408
#define AHI 34816
#define ALO 43008
__global__ __launch_bounds__(256) void conv_mfma_kernel(
    const float* __restrict__ gv, const float* __restrict__ ca,
    const unsigned short* __restrict__ Whi, const unsigned short* __restrict__ Wlo,
    float* __restrict__ out)
{
    __shared__ char smem[51200];
    const int b   = blockIdx.z;
    const int h0  = blockIdx.y * 2;
    const int o0  = blockIdx.x * 64;
    const int tid = threadIdx.x;
    const int l   = tid & 63;
    const int wv  = tid >> 6;
    const int wy  = wv >> 1;    // o half within block
    const int wx  = wv & 1;     // image row within tile
    const int ln  = l & 15;
    const int quad = l >> 4;

    f32x4 acc[2][2];
    #pragma unroll
    for (int i = 0; i < 2; ++i)
        #pragma unroll
        for (int j = 0; j < 2; ++j)
            acc[i][j] = (f32x4){0.f, 0.f, 0.f, 0.f};

    for (int half = 0; half < 2; ++half) {
        __syncthreads();   // protect B planes from readers of previous half
        // ---- stage B planes: 136 pxslots x 64 ci, gv*ca -> bf16 hi/lo
        for (int u = tid; u < 136 * 16; u += 256) {
            int p   = u >> 4;
            int ciq = u & 15;
            int hrel = p / 34;
            int c    = p - hrel * 34;
            int gr = h0 + hrel - 1;
            int gc = c - 1;
            bool ok = ((unsigned)gr < 32u) && ((unsigned)gc < 32u);
            int cib = half * 64 + ciq * 4;
            unsigned int hx = 0, hy = 0, lx = 0, ly = 0;
            #pragma unroll
            for (int t = 0; t < 4; ++t) {
                float v = 0.0f;
                if (ok)
                    v = gv[(size_t)(b * CI_ + cib + t) * N_ + gr * 32 + gc]
                        * ca[b * CI_ + cib + t];
                unsigned short h = f2bf_rne(v);
                unsigned short lo = f2bf_rne(v - bf2f(h));
                if (t < 2) { hx |= ((unsigned)h) << (16 * t); lx |= ((unsigned)lo) << (16 * t); }
                else       { hy |= ((unsigned)h) << (16 * (t - 2)); ly |= ((unsigned)lo) << (16 * (t - 2)); }
            }
            int addr = p * 128 + (((ciq >> 1) ^ (p & 7)) << 4) + ((ciq & 1) << 3);
            *(uint2*)&smem[BHI + addr] = make_uint2(hx, hy);
            *(uint2*)&smem[BLO + addr] = make_uint2(lx, ly);
        }
        for (int tap = 0; tap < 9; ++tap) {
            __syncthreads();   // A overwrite safety + B visibility (tap 0)
            // ---- stage A planes: 64 o x 64 ci (this half), tap fixed
            #pragma unroll
            for (int it = 0; it < 2; ++it) {
                int row = it * 32 + (tid >> 3);
                int s   = tid & 7;
                int csrc = s ^ (row & 7);
                size_t gsrc = (size_t)(o0 + row) * 1152 + tap * 128 + half * 64 + csrc * 8;
                int la = row * 128 + s * 16;
                *(uint4*)&smem[AHI + la] = *(const uint4*)&Whi[gsrc];
                *(uint4*)&smem[ALO + la] = *(const uint4*)&Wlo[gsrc];
            }
            __syncthreads();
            const int dy = tap / 3, dx = tap - dy * 3;
            const int pbase = (wx + dy) * 34 + dx;
            #pragma unroll
            for (int cc = 0; cc < 2; ++cc) {
                v8bf Bh[2], Bl[2], Ah[2], Al[2];
                #pragma unroll
                for (int j = 0; j < 2; ++j) {
                    int p = pbase + j * 16 + ln;
                    int ch = cc * 4 + quad;
                    int addr = p * 128 + ((ch ^ (p & 7)) << 4);
                    Bh[j] = *(const v8bf*)&smem[BHI + addr];
                    Bl[j] = *(const v8bf*)&smem[BLO + addr];
                }
                #pragma unroll
                for (int i = 0; i < 2; ++i) {
                    int o = wy * 32 + i * 16 + ln;
                    int ch = cc * 4 + quad;
                    int addr = o * 128 + ((ch ^ (o & 7)) << 4);
                    Ah[i] = *(const v8bf*)&smem[AHI + addr];
                    Al[i] = *(const v8bf*)&smem[ALO + addr];
                }
                #pragma unroll
                for (int i = 0; i < 2; ++i)
                    #pragma unroll
                    for (int j = 0; j < 2; ++j) {
                        acc[i][j] = __builtin_amdgcn_mfma_f32_16x16x32_bf16(Ah[i], Bh[j], acc[i][j], 0, 0, 0);
                        acc[i][j] = __builtin_amdgcn_mfma_f32_16x16x32_bf16(Ah[i], Bl[j], acc[i][j], 0, 0, 0);
                        acc[i][j] = __builtin_amdgcn_mfma_f32_16x16x32_bf16(Al[i], Bh[j], acc[i][j], 0, 0, 0);
                    }
            }
        }
    }

    // ---- epilogue: C/D layout col = lane&15 (px), row = quad*4+reg (o)
    const int h = h0 + wx;
    #pragma unroll
    for (int i = 0; i < 2; ++i)
        #pragma unroll
        for (int j = 0; j < 2; ++j)
            #pragma unroll
            for (int r = 0; r < 4; ++r) {
                int o = o0 + wy * 32 + i * 16 + quad * 4 + r;
                int w = j * 16 + ln;
                out[(size_t)(b * CO_ + o) * N_ + h * 32 + w] = acc[i][j][r];
            }
}

// ---------------------------------------------------------------------------
extern "C" void kernel_launch(void* const* d_in, const int* in_sizes, int n_in,
                              void* d_out, int out_size, void* d_ws, size_t ws_size,
                              hipStream_t stream) {
    const float* x   = (const float*)d_in[0];
    const float* Wq  = (const float*)d_in[1];
    const float* Wk  = (const float*)d_in[2];
    const float* Wv  = (const float*)d_in[3];
    const float* w1d = (const float*)d_in[4];
    const float* Wc  = (const float*)d_in[5];

    float* out  = (float*)d_out;
    float* gate = out + 2097152;
    float* ca   = gate + 8388608;

    float* qkv   = (float*)d_ws;                    // 3145728 floats
    float* gv    = qkv + 3145728;                   // 1048576 floats
    float* meanb = gv + 1048576;                    // 1024 floats
    unsigned short* Whi = (unsigned short*)(meanb + 1024);   // 294912 ushorts
    unsigned short* Wlo = Whi + 294912;                      // 294912 ushorts

    prep_w_kernel<<<dim3(1152), 256, 0, stream>>>(Wc, Whi, Wlo);
    proj_kernel<<<dim3(16, 6, 8), 256, 0, stream>>>(x, Wq, Wk, Wv, qkv);
    scores_kernel<<<dim3(16, 16, 8), 256, 0, stream>>>(qkv, gate);
    softmax_kernel<<<dim3(1024, 8), 256, 0, stream>>>(gate);
    hipMemsetAsync(gv, 0, (size_t)1048576 * sizeof(float), stream);
    gv_kernel<<<dim3(16, 2, 16), 256, 0, stream>>>(qkv, gate, gv);
    mean_kernel<<<dim3(128, 8), 256, 0, stream>>>(gv, meanb);
    ca_kernel<<<1, 1024, 0, stream>>>(meanb, w1d, ca);
    conv_mfma_kernel<<<dim3(4, 16, 8), 256, 0, stream>>>(gv, ca, Whi, Wlo, out);
}

// Round 3
// 338.328 us; speedup vs baseline: 1.8636x; 1.0823x over previous
//
#include <hip/hip_runtime.h>
#include <math.h>

#define B_   8
#define C_   256
#define CI_  128
#define N_   1024
#define HW_  32
#define CO_  256

typedef __bf16 v8bf __attribute__((ext_vector_type(8)));
typedef float  f32x4 __attribute__((ext_vector_type(4)));
typedef unsigned short ushort_t;

__device__ __forceinline__ unsigned short f2bf_rne(float f) {
    unsigned int u = __float_as_uint(f);
    unsigned int r = u + 0x7FFF + ((u >> 16) & 1);
    return (unsigned short)(r >> 16);
}
__device__ __forceinline__ float bf2f(unsigned short h) {
    return __uint_as_float(((unsigned int)h) << 16);
}
__device__ __forceinline__ v8bf ld8(const ushort_t* p) {
    return *(const v8bf*)p;
}

// ---------------------------------------------------------------------------
// P1: split Wc into bf16 hi/lo [o][tap][ci]  AND  Wq/Wk/Wv into Wp hi/lo [384][256]
__global__ __launch_bounds__(256) void prep_w_kernel(
    const float* __restrict__ Wc,
    const float* __restrict__ Wq, const float* __restrict__ Wk,
    const float* __restrict__ Wv,
    ushort_t* __restrict__ Whi, ushort_t* __restrict__ Wlo,
    ushort_t* __restrict__ Wp_hi, ushort_t* __restrict__ Wp_lo)
{
    if (blockIdx.x < 1152) {
        int idx = blockIdx.x * 256 + threadIdx.x;     // 294912
        int o = idx / 1152;
        int r = idx - o * 1152;
        int ci = r / 9;
        int tap = r - ci * 9;
        float v = Wc[idx];
        unsigned short h = f2bf_rne(v);
        unsigned short l = f2bf_rne(v - bf2f(h));
        int didx = o * 1152 + tap * 128 + ci;
        Whi[didx] = h; Wlo[didx] = l;
    } else {
        int j = (blockIdx.x - 1152) * 256 + threadIdx.x;  // 98304
        int o = j >> 8, c = j & 255;
        float v = (o < 128) ? Wq[o * 256 + c]
                : (o < 256) ? Wk[(o - 128) * 256 + c]
                            : Wv[(o - 256) * 256 + c];
        unsigned short h = f2bf_rne(v);
        unsigned short l = f2bf_rne(v - bf2f(h));
        Wp_hi[j] = h; Wp_lo[j] = l;
    }
}

// ---------------------------------------------------------------------------
// P2: gather strided x -> xs_t[b][n][c] bf16 hi/lo (transposed via LDS)
__global__ __launch_bounds__(256) void prep_x_kernel(
    const float* __restrict__ x,
    ushort_t* __restrict__ xs_hi, ushort_t* __restrict__ xs_lo)
{
    __shared__ ushort_t lh[32 * 264];
    __shared__ ushort_t ll[32 * 264];
    const int h = blockIdx.x, b = blockIdx.y;
    const int tid = threadIdx.x;
    const int w = tid & 31, cg = tid >> 5;
    for (int c0 = 0; c0 < 256; c0 += 8) {
        int c = c0 + cg;
        float v = x[((size_t)(b * C_ + c) * 128 + h * 4) * 128 + w * 4];
        unsigned short hi = f2bf_rne(v);
        unsigned short lo = f2bf_rne(v - bf2f(hi));
        lh[w * 264 + c] = hi;
        ll[w * 264 + c] = lo;
    }
    __syncthreads();
    const int ww = tid >> 3, cs = tid & 7;
    size_t dst = ((size_t)(b * N_) + h * 32 + ww) * 256 + cs * 32;
    #pragma unroll
    for (int t = 0; t < 4; ++t) {
        *(uint4*)&xs_hi[dst + t * 8] = *(uint4*)&lh[ww * 264 + cs * 32 + t * 8];
        *(uint4*)&xs_lo[dst + t * 8] = *(uint4*)&ll[ww * 264 + cs * 32 + t * 8];
    }
}

// ---------------------------------------------------------------------------
// K1: proj MFMA. A = Wp [o][c] hi/lo, B = xs_t [n][c] hi/lo. 3-term split.
// Writes q,k transposed [n][o] hi/lo; v natural [c][n] hi/lo.
__global__ __launch_bounds__(256) void proj_mfma_kernel(
    const ushort_t* __restrict__ Wp_hi, const ushort_t* __restrict__ Wp_lo,
    const ushort_t* __restrict__ xs_hi, const ushort_t* __restrict__ xs_lo,
    ushort_t* __restrict__ qt_hi, ushort_t* __restrict__ qt_lo,
    ushort_t* __restrict__ kt_hi, ushort_t* __restrict__ kt_lo,
    ushort_t* __restrict__ v_hi,  ushort_t* __restrict__ v_lo)
{
    const int n0 = blockIdx.x * 64;
    const int o0 = blockIdx.y * 64;
    const int b  = blockIdx.z;
    const int tid = threadIdx.x;
    const int l = tid & 63, wv = tid >> 6;
    const int wy = wv >> 1, wx = wv & 1;
    const int ln = l & 15, quad = l >> 4;

    f32x4 acc[2][2];
    #pragma unroll
    for (int i = 0; i < 2; ++i)
        #pragma unroll
        for (int j = 0; j < 2; ++j) acc[i][j] = (f32x4){0.f,0.f,0.f,0.f};

    const ushort_t* Ah_p[2]; const ushort_t* Al_p[2];
    const ushort_t* Bh_p[2]; const ushort_t* Bl_p[2];
    #pragma unroll
    for (int i = 0; i < 2; ++i) {
        size_t off = (size_t)(o0 + wy * 32 + i * 16 + ln) * 256 + quad * 8;
        Ah_p[i] = Wp_hi + off; Al_p[i] = Wp_lo + off;
    }
    #pragma unroll
    for (int j = 0; j < 2; ++j) {
        size_t off = ((size_t)(b * N_) + n0 + wx * 32 + j * 16 + ln) * 256 + quad * 8;
        Bh_p[j] = xs_hi + off; Bl_p[j] = xs_lo + off;
    }

    #pragma unroll 4
    for (int k0 = 0; k0 < 256; k0 += 32) {
        v8bf Ah[2], Al[2], Bh[2], Bl[2];
        #pragma unroll
        for (int i = 0; i < 2; ++i) { Ah[i] = ld8(Ah_p[i] + k0); Al[i] = ld8(Al_p[i] + k0); }
        #pragma unroll
        for (int j = 0; j < 2; ++j) { Bh[j] = ld8(Bh_p[j] + k0); Bl[j] = ld8(Bl_p[j] + k0); }
        #pragma unroll
        for (int i = 0; i < 2; ++i)
            #pragma unroll
            for (int j = 0; j < 2; ++j) {
                acc[i][j] = __builtin_amdgcn_mfma_f32_16x16x32_bf16(Ah[i], Bh[j], acc[i][j], 0, 0, 0);
                acc[i][j] = __builtin_amdgcn_mfma_f32_16x16x32_bf16(Ah[i], Bl[j], acc[i][j], 0, 0, 0);
                acc[i][j] = __builtin_amdgcn_mfma_f32_16x16x32_bf16(Al[i], Bh[j], acc[i][j], 0, 0, 0);
            }
    }

    if (o0 < 256) {
        // q or k: transposed store [n][o], pack 4 consecutive o (regs) into 8B
        ushort_t* th = (o0 < 128) ? qt_hi : kt_hi;
        ushort_t* tl = (o0 < 128) ? qt_lo : kt_lo;
        const int ob = o0 & 127;
        #pragma unroll
        for (int i = 0; i < 2; ++i)
            #pragma unroll
            for (int j = 0; j < 2; ++j) {
                int oo = ob + wy * 32 + i * 16 + quad * 4;
                int n  = n0 + wx * 32 + j * 16 + ln;
                unsigned int h01 = 0, h23 = 0, l01 = 0, l23 = 0;
                #pragma unroll
                for (int r = 0; r < 4; ++r) {
                    float f = acc[i][j][r];
                    unsigned short hh = f2bf_rne(f);
                    unsigned short lo = f2bf_rne(f - bf2f(hh));
                    if (r < 2) { h01 |= ((unsigned)hh) << (16 * r); l01 |= ((unsigned)lo) << (16 * r); }
                    else       { h23 |= ((unsigned)hh) << (16 * (r - 2)); l23 |= ((unsigned)lo) << (16 * (r - 2)); }
                }
                size_t off = ((size_t)(b * N_) + n) * 128 + oo;
                *(uint2*)&th[off] = make_uint2(h01, h23);
                *(uint2*)&tl[off] = make_uint2(l01, l23);
            }
    } else {
        #pragma unroll
        for (int i = 0; i < 2; ++i)
            #pragma unroll
            for (int j = 0; j < 2; ++j)
                #pragma unroll
                for (int r = 0; r < 4; ++r) {
                    int c = (o0 - 256) + wy * 32 + i * 16 + quad * 4 + r;
                    int n = n0 + wx * 32 + j * 16 + ln;
                    float f = acc[i][j][r];
                    unsigned short hh = f2bf_rne(f);
                    unsigned short lo = f2bf_rne(f - bf2f(hh));
                    size_t off = (size_t)(b * CI_ + c) * N_ + n;
                    v_hi[off] = hh; v_lo[off] = lo;
                }
    }
}

// ---------------------------------------------------------------------------
// K2: scores MFMA. A = qt [n][c] hi/lo, B = kt [m][c] hi/lo, K=128. 3-term.
__global__ __launch_bounds__(256) void scores_mfma_kernel(
    const ushort_t* __restrict__ qt_hi, const ushort_t* __restrict__ qt_lo,
    const ushort_t* __restrict__ kt_hi, const ushort_t* __restrict__ kt_lo,
    float* __restrict__ gate)
{
    const int m0 = blockIdx.x * 64;
    const int n0 = blockIdx.y * 64;
    const int b  = blockIdx.z;
    const int tid = threadIdx.x;
    const int l = tid & 63, wv = tid >> 6;
    const int wy = wv >> 1, wx = wv & 1;
    const int ln = l & 15, quad = l >> 4;

    f32x4 acc[2][2];
    #pragma unroll
    for (int i = 0; i < 2; ++i)
        #pragma unroll
        for (int j = 0; j < 2; ++j) acc[i][j] = (f32x4){0.f,0.f,0.f,0.f};

    const ushort_t* Ah_p[2]; const ushort_t* Al_p[2];
    const ushort_t* Bh_p[2]; const ushort_t* Bl_p[2];
    #pragma unroll
    for (int i = 0; i < 2; ++i) {
        size_t off = ((size_t)(b * N_) + n0 + wy * 32 + i * 16 + ln) * 128 + quad * 8;
        Ah_p[i] = qt_hi + off; Al_p[i] = qt_lo + off;
    }
    #pragma unroll
    for (int j = 0; j < 2; ++j) {
        size_t off = ((size_t)(b * N_) + m0 + wx * 32 + j * 16 + ln) * 128 + quad * 8;
        Bh_p[j] = kt_hi + off; Bl_p[j] = kt_lo + off;
    }

    #pragma unroll
    for (int k0 = 0; k0 < 128; k0 += 32) {
        v8bf Ah[2], Al[2], Bh[2], Bl[2];
        #pragma unroll
        for (int i = 0; i < 2; ++i) { Ah[i] = ld8(Ah_p[i] + k0); Al[i] = ld8(Al_p[i] + k0); }
        #pragma unroll
        for (int j = 0; j < 2; ++j) { Bh[j] = ld8(Bh_p[j] + k0); Bl[j] = ld8(Bl_p[j] + k0); }
        #pragma unroll
        for (int i = 0; i < 2; ++i)
            #pragma unroll
            for (int j = 0; j < 2; ++j) {
                acc[i][j] = __builtin_amdgcn_mfma_f32_16x16x32_bf16(Ah[i], Bh[j], acc[i][j], 0, 0, 0);
                acc[i][j] = __builtin_amdgcn_mfma_f32_16x16x32_bf16(Ah[i], Bl[j], acc[i][j], 0, 0, 0);
                acc[i][j] = __builtin_amdgcn_mfma_f32_16x16x32_bf16(Al[i], Bh[j], acc[i][j], 0, 0, 0);
            }
    }

    #pragma unroll
    for (int i = 0; i < 2; ++i)
        #pragma unroll
        for (int j = 0; j < 2; ++j)
            #pragma unroll
            for (int r = 0; r < 4; ++r) {
                int n = n0 + wy * 32 + i * 16 + quad * 4 + r;
                int m = m0 + wx * 32 + j * 16 + ln;
                gate[((size_t)(b * N_) + n) * N_ + m] = acc[i][j][r];
            }
}

// ---------------------------------------------------------------------------
// K3: softmax in-place + bf16 copy for gv's B operand
__global__ __launch_bounds__(256) void softmax_kernel(
    float* __restrict__ gate, ushort_t* __restrict__ gate_bf)
{
    const int n = blockIdx.x, b = blockIdx.y;
    float* row = gate + ((size_t)(b * N_ + n)) * N_;
    ushort_t* rowbf = gate_bf + ((size_t)(b * N_ + n)) * N_;
    const int tid = threadIdx.x;
    const int wid = tid >> 6, lane = tid & 63;
    __shared__ float redm[4];
    __shared__ float reds[4];

    float4 v = ((const float4*)row)[tid];
    float m = fmaxf(fmaxf(v.x, v.y), fmaxf(v.z, v.w));
    #pragma unroll
    for (int off = 32; off; off >>= 1) m = fmaxf(m, __shfl_xor(m, off, 64));
    if (lane == 0) redm[wid] = m;
    __syncthreads();
    m = fmaxf(fmaxf(redm[0], redm[1]), fmaxf(redm[2], redm[3]));

    float4 e;
    e.x = __expf(v.x - m); e.y = __expf(v.y - m);
    e.z = __expf(v.z - m); e.w = __expf(v.w - m);
    float s = e.x + e.y + e.z + e.w;
    #pragma unroll
    for (int off = 32; off; off >>= 1) s += __shfl_xor(s, off, 64);
    if (lane == 0) reds[wid] = s;
    __syncthreads();
    s = reds[0] + reds[1] + reds[2] + reds[3];
    float inv = 1.0f / s;
    e.x *= inv; e.y *= inv; e.z *= inv; e.w *= inv;
    ((float4*)row)[tid] = e;
    unsigned int p0 = (unsigned)f2bf_rne(e.x) | (((unsigned)f2bf_rne(e.y)) << 16);
    unsigned int p1 = (unsigned)f2bf_rne(e.z) | (((unsigned)f2bf_rne(e.w)) << 16);
    ((uint2*)rowbf)[tid] = make_uint2(p0, p1);
}

// ---------------------------------------------------------------------------
// K4: gv MFMA. A = v [c][m] hi/lo, B = gate_bf [n][m]. 2-term (Ah*B + Al*B).
// Block: 64c x 32n; wave = 32c x 16n. K=1024.
__global__ __launch_bounds__(256) void gv_mfma_kernel(
    const ushort_t* __restrict__ v_hi, const ushort_t* __restrict__ v_lo,
    const ushort_t* __restrict__ gate_bf, float* __restrict__ gv)
{
    const int n0 = blockIdx.x * 32;
    const int c0 = blockIdx.y * 64;
    const int b  = blockIdx.z;
    const int tid = threadIdx.x;
    const int l = tid & 63, wv = tid >> 6;
    const int wy = wv >> 1, wx = wv & 1;
    const int ln = l & 15, quad = l >> 4;

    f32x4 acc[2];
    acc[0] = (f32x4){0.f,0.f,0.f,0.f};
    acc[1] = (f32x4){0.f,0.f,0.f,0.f};

    const ushort_t* Ah_p[2]; const ushort_t* Al_p[2];
    #pragma unroll
    for (int i = 0; i < 2; ++i) {
        size_t off = (size_t)(b * CI_ + c0 + wy * 32 + i * 16 + ln) * N_ + quad * 8;
        Ah_p[i] = v_hi + off; Al_p[i] = v_lo + off;
    }
    const ushort_t* B_p = gate_bf + ((size_t)(b * N_) + n0 + wx * 16 + ln) * N_ + quad * 8;

    #pragma unroll 4
    for (int m0 = 0; m0 < 1024; m0 += 32) {
        v8bf Bh = ld8(B_p + m0);
        #pragma unroll
        for (int i = 0; i < 2; ++i) {
            v8bf Ah = ld8(Ah_p[i] + m0);
            v8bf Al = ld8(Al_p[i] + m0);
            acc[i] = __builtin_amdgcn_mfma_f32_16x16x32_bf16(Ah, Bh, acc[i], 0, 0, 0);
            acc[i] = __builtin_amdgcn_mfma_f32_16x16x32_bf16(Al, Bh, acc[i], 0, 0, 0);
        }
    }

    #pragma unroll
    for (int i = 0; i < 2; ++i)
        #pragma unroll
        for (int r = 0; r < 4; ++r) {
            int c = c0 + wy * 32 + i * 16 + quad * 4 + r;
            int n = n0 + wx * 16 + ln;
            gv[(size_t)(b * CI_ + c) * N_ + n] = acc[i][r];
        }
}

// ---------------------------------------------------------------------------
// K5: mean
__global__ __launch_bounds__(256) void mean_kernel(
    const float* __restrict__ gv, float* __restrict__ meanb)
{
    const int i = blockIdx.x, b = blockIdx.y;
    const int tid = threadIdx.x;
    const int wid = tid >> 6, lane = tid & 63;
    __shared__ float red[4];
    const float* base = gv + (size_t)(b * CI_ + i) * N_;
    float4 v = ((const float4*)base)[tid];
    float s = v.x + v.y + v.z + v.w;
    #pragma unroll
    for (int off = 32; off; off >>= 1) s += __shfl_xor(s, off, 64);
    if (lane == 0) red[wid] = s;
    __syncthreads();
    if (tid == 0)
        meanb[b * CI_ + i] = (red[0] + red[1] + red[2] + red[3]) * (1.0f / 1024.0f);
}

// ---------------------------------------------------------------------------
// K6: conv1d + sigmoid
__global__ __launch_bounds__(1024) void ca_kernel(
    const float* __restrict__ meanb, const float* __restrict__ w1d,
    float* __restrict__ ca)
{
    const int t = threadIdx.x;
    const int i = t & 127;
    float left  = (i > 0)   ? meanb[t - 1] : 0.0f;
    float mid   = meanb[t];
    float right = (i < 127) ? meanb[t + 1] : 0.0f;
    float val = w1d[0] * left + w1d[1] * mid + w1d[2] * right;
    ca[t] = 1.0f / (1.0f + __expf(-val));
}

// ---------------------------------------------------------------------------
// K7: MFMA conv (unchanged from R2)
#define BHI 0
#define BLO 17408
#define AHI 34816
#define ALO 43008
__global__ __launch_bounds__(256) void conv_mfma_kernel(
    const float* __restrict__ gv, const float* __restrict__ ca,
    const ushort_t* __restrict__ Whi, const ushort_t* __restrict__ Wlo,
    float* __restrict__ out)
{
    __shared__ char smem[51200];
    const int b   = blockIdx.z;
    const int h0  = blockIdx.y * 2;
    const int o0  = blockIdx.x * 64;
    const int tid = threadIdx.x;
    const int l   = tid & 63;
    const int wv  = tid >> 6;
    const int wy  = wv >> 1;
    const int wx  = wv & 1;
    const int ln  = l & 15;
    const int quad = l >> 4;

    f32x4 acc[2][2];
    #pragma unroll
    for (int i = 0; i < 2; ++i)
        #pragma unroll
        for (int j = 0; j < 2; ++j)
            acc[i][j] = (f32x4){0.f, 0.f, 0.f, 0.f};

    for (int half = 0; half < 2; ++half) {
        __syncthreads();
        for (int u = tid; u < 136 * 16; u += 256) {
            int p   = u >> 4;
            int ciq = u & 15;
            int hrel = p / 34;
            int c    = p - hrel * 34;
            int gr = h0 + hrel - 1;
            int gc = c - 1;
            bool ok = ((unsigned)gr < 32u) && ((unsigned)gc < 32u);
            int cib = half * 64 + ciq * 4;
            unsigned int hx = 0, hy = 0, lx = 0, ly = 0;
            #pragma unroll
            for (int t = 0; t < 4; ++t) {
                float v = 0.0f;
                if (ok)
                    v = gv[(size_t)(b * CI_ + cib + t) * N_ + gr * 32 + gc]
                        * ca[b * CI_ + cib + t];
                unsigned short h = f2bf_rne(v);
                unsigned short lo = f2bf_rne(v - bf2f(h));
                if (t < 2) { hx |= ((unsigned)h) << (16 * t); lx |= ((unsigned)lo) << (16 * t); }
                else       { hy |= ((unsigned)h) << (16 * (t - 2)); ly |= ((unsigned)lo) << (16 * (t - 2)); }
            }
            int addr = p * 128 + (((ciq >> 1) ^ (p & 7)) << 4) + ((ciq & 1) << 3);
            *(uint2*)&smem[BHI + addr] = make_uint2(hx, hy);
            *(uint2*)&smem[BLO + addr] = make_uint2(lx, ly);
        }
        for (int tap = 0; tap < 9; ++tap) {
            __syncthreads();
            #pragma unroll
            for (int it = 0; it < 2; ++it) {
                int row = it * 32 + (tid >> 3);
                int s   = tid & 7;
                int csrc = s ^ (row & 7);
                size_t gsrc = (size_t)(o0 + row) * 1152 + tap * 128 + half * 64 + csrc * 8;
                int la = row * 128 + s * 16;
                *(uint4*)&smem[AHI + la] = *(const uint4*)&Whi[gsrc];
                *(uint4*)&smem[ALO + la] = *(const uint4*)&Wlo[gsrc];
            }
            __syncthreads();
            const int dy = tap / 3, dx = tap - dy * 3;
            const int pbase = (wx + dy) * 34 + dx;
            #pragma unroll
            for (int cc = 0; cc < 2; ++cc) {
                v8bf Bh[2], Bl[2], Ah[2], Al[2];
                #pragma unroll
                for (int j = 0; j < 2; ++j) {
                    int p = pbase + j * 16 + ln;
                    int ch = cc * 4 + quad;
                    int addr = p * 128 + ((ch ^ (p & 7)) << 4);
                    Bh[j] = *(const v8bf*)&smem[BHI + addr];
                    Bl[j] = *(const v8bf*)&smem[BLO + addr];
                }
                #pragma unroll
                for (int i = 0; i < 2; ++i) {
                    int o = wy * 32 + i * 16 + ln;
                    int ch = cc * 4 + quad;
                    int addr = o * 128 + ((ch ^ (o & 7)) << 4);
                    Ah[i] = *(const v8bf*)&smem[AHI + addr];
                    Al[i] = *(const v8bf*)&smem[ALO + addr];
                }
                #pragma unroll
                for (int i = 0; i < 2; ++i)
                    #pragma unroll
                    for (int j = 0; j < 2; ++j) {
                        acc[i][j] = __builtin_amdgcn_mfma_f32_16x16x32_bf16(Ah[i], Bh[j], acc[i][j], 0, 0, 0);
                        acc[i][j] = __builtin_amdgcn_mfma_f32_16x16x32_bf16(Ah[i], Bl[j], acc[i][j], 0, 0, 0);
                        acc[i][j] = __builtin_amdgcn_mfma_f32_16x16x32_bf16(Al[i], Bh[j], acc[i][j], 0, 0, 0);
                    }
            }
        }
    }

    const int h = h0 + wx;
    #pragma unroll
    for (int i = 0; i < 2; ++i)
        #pragma unroll
        for (int j = 0; j < 2; ++j)
            #pragma unroll
            for (int r = 0; r < 4; ++r) {
                int o = o0 + wy * 32 + i * 16 + quad * 4 + r;
                int w = j * 16 + ln;
                out[(size_t)(b * CO_ + o) * N_ + h * 32 + w] = acc[i][j][r];
            }
}

// ---------------------------------------------------------------------------
extern "C" void kernel_launch(void* const* d_in, const int* in_sizes, int n_in,
                              void* d_out, int out_size, void* d_ws, size_t ws_size,
                              hipStream_t stream) {
    const float* x   = (const float*)d_in[0];
    const float* Wq  = (const float*)d_in[1];
    const float* Wk  = (const float*)d_in[2];
    const float* Wv  = (const float*)d_in[3];
    const float* w1d = (const float*)d_in[4];
    const float* Wc  = (const float*)d_in[5];

    float* out  = (float*)d_out;
    float* gate = out + 2097152;
    float* ca   = gate + 8388608;

    float*    gv      = (float*)d_ws;            // 1048576 f
    float*    meanb   = gv + 1048576;            // 1024 f
    ushort_t* Whi     = (ushort_t*)(meanb + 1024);   // 294912
    ushort_t* Wlo     = Whi + 294912;
    ushort_t* Wp_hi   = Wlo + 294912;            // 98304
    ushort_t* Wp_lo   = Wp_hi + 98304;
    ushort_t* xs_hi   = Wp_lo + 98304;           // 2097152
    ushort_t* xs_lo   = xs_hi + 2097152;
    ushort_t* qt_hi   = xs_lo + 2097152;         // 1048576
    ushort_t* qt_lo   = qt_hi + 1048576;
    ushort_t* kt_hi   = qt_lo + 1048576;
    ushort_t* kt_lo   = kt_hi + 1048576;
    ushort_t* v_hi    = kt_lo + 1048576;
    ushort_t* v_lo    = v_hi + 1048576;
    ushort_t* gate_bf = v_lo + 1048576;          // 8388608

    prep_w_kernel<<<dim3(1536), 256, 0, stream>>>(Wc, Wq, Wk, Wv, Whi, Wlo, Wp_hi, Wp_lo);
    prep_x_kernel<<<dim3(32, 8), 256, 0, stream>>>(x, xs_hi, xs_lo);
    proj_mfma_kernel<<<dim3(16, 6, 8), 256, 0, stream>>>(
        Wp_hi, Wp_lo, xs_hi, xs_lo, qt_hi, qt_lo, kt_hi, kt_lo, v_hi, v_lo);
    scores_mfma_kernel<<<dim3(16, 16, 8), 256, 0, stream>>>(qt_hi, qt_lo, kt_hi, kt_lo, gate);
    softmax_kernel<<<dim3(1024, 8), 256, 0, stream>>>(gate, gate_bf);
    gv_mfma_kernel<<<dim3(32, 2, 8), 256, 0, stream>>>(v_hi, v_lo, gate_bf, gv);
    mean_kernel<<<dim3(128, 8), 256, 0, stream>>>(gv, meanb);
    ca_kernel<<<1, 1024, 0, stream>>>(meanb, w1d, ca);
    conv_mfma_kernel<<<dim3(4, 16, 8), 256, 0, stream>>>(gv, ca, Whi, Wlo, out);
}

// Round 4
// 304.369 us; speedup vs baseline: 2.0715x; 1.1116x over previous
//
#include <hip/hip_runtime.h>
#include <math.h>

#define B_   8
#define C_   256
#define CI_  128
#define N_   1024
#define HW_  32
#define CO_  256

typedef __bf16 v8bf __attribute__((ext_vector_type(8)));
typedef float  f32x4 __attribute__((ext_vector_type(4)));
typedef unsigned short ushort_t;

__device__ __forceinline__ unsigned short f2bf_rne(float f) {
    unsigned int u = __float_as_uint(f);
    unsigned int r = u + 0x7FFF + ((u >> 16) & 1);
    return (unsigned short)(r >> 16);
}
__device__ __forceinline__ float bf2f(unsigned short h) {
    return __uint_as_float(((unsigned int)h) << 16);
}
__device__ __forceinline__ v8bf ld8(const ushort_t* p) {
    return *(const v8bf*)p;
}

// ---------------------------------------------------------------------------
// P1: split Wc into bf16 hi/lo [o][tap][ci]  AND  Wq/Wk/Wv into Wp hi/lo [384][256]
__global__ __launch_bounds__(256) void prep_w_kernel(
    const float* __restrict__ Wc,
    const float* __restrict__ Wq, const float* __restrict__ Wk,
    const float* __restrict__ Wv,
    ushort_t* __restrict__ Whi, ushort_t* __restrict__ Wlo,
    ushort_t* __restrict__ Wp_hi, ushort_t* __restrict__ Wp_lo)
{
    if (blockIdx.x < 1152) {
        int idx = blockIdx.x * 256 + threadIdx.x;     // 294912
        int o = idx / 1152;
        int r = idx - o * 1152;
        int ci = r / 9;
        int tap = r - ci * 9;
        float v = Wc[idx];
        unsigned short h = f2bf_rne(v);
        unsigned short l = f2bf_rne(v - bf2f(h));
        int didx = o * 1152 + tap * 128 + ci;
        Whi[didx] = h; Wlo[didx] = l;
    } else {
        int j = (blockIdx.x - 1152) * 256 + threadIdx.x;  // 98304
        int o = j >> 8, c = j & 255;
        float v = (o < 128) ? Wq[o * 256 + c]
                : (o < 256) ? Wk[(o - 128) * 256 + c]
                            : Wv[(o - 256) * 256 + c];
        unsigned short h = f2bf_rne(v);
        unsigned short l = f2bf_rne(v - bf2f(h));
        Wp_hi[j] = h; Wp_lo[j] = l;
    }
}

// ---------------------------------------------------------------------------
// P2: gather strided x -> xs_t[b][n][c] bf16 hi/lo (transposed via LDS)
__global__ __launch_bounds__(256) void prep_x_kernel(
    const float* __restrict__ x,
    ushort_t* __restrict__ xs_hi, ushort_t* __restrict__ xs_lo)
{
    __shared__ ushort_t lh[32 * 264];
    __shared__ ushort_t ll[32 * 264];
    const int h = blockIdx.x, b = blockIdx.y;
    const int tid = threadIdx.x;
    const int w = tid & 31, cg = tid >> 5;
    for (int c0 = 0; c0 < 256; c0 += 8) {
        int c = c0 + cg;
        float v = x[((size_t)(b * C_ + c) * 128 + h * 4) * 128 + w * 4];
        unsigned short hi = f2bf_rne(v);
        unsigned short lo = f2bf_rne(v - bf2f(hi));
        lh[w * 264 + c] = hi;
        ll[w * 264 + c] = lo;
    }
    __syncthreads();
    const int ww = tid >> 3, cs = tid & 7;
    size_t dst = ((size_t)(b * N_) + h * 32 + ww) * 256 + cs * 32;
    #pragma unroll
    for (int t = 0; t < 4; ++t) {
        *(uint4*)&xs_hi[dst + t * 8] = *(uint4*)&lh[ww * 264 + cs * 32 + t * 8];
        *(uint4*)&xs_lo[dst + t * 8] = *(uint4*)&ll[ww * 264 + cs * 32 + t * 8];
    }
}

// ---------------------------------------------------------------------------
// K1: proj MFMA. A = Wp [o][c] hi/lo, B = xs_t [n][c] hi/lo. 3-term split.
// Writes q,k transposed [n][o] hi/lo; v in packed layout vB[b][m>>5][c][m&31].
__global__ __launch_bounds__(256) void proj_mfma_kernel(
    const ushort_t* __restrict__ Wp_hi, const ushort_t* __restrict__ Wp_lo,
    const ushort_t* __restrict__ xs_hi, const ushort_t* __restrict__ xs_lo,
    ushort_t* __restrict__ qt_hi, ushort_t* __restrict__ qt_lo,
    ushort_t* __restrict__ kt_hi, ushort_t* __restrict__ kt_lo,
    ushort_t* __restrict__ vB_hi, ushort_t* __restrict__ vB_lo)
{
    const int n0 = blockIdx.x * 64;
    const int o0 = blockIdx.y * 64;
    const int b  = blockIdx.z;
    const int tid = threadIdx.x;
    const int l = tid & 63, wv = tid >> 6;
    const int wy = wv >> 1, wx = wv & 1;
    const int ln = l & 15, quad = l >> 4;

    f32x4 acc[2][2];
    #pragma unroll
    for (int i = 0; i < 2; ++i)
        #pragma unroll
        for (int j = 0; j < 2; ++j) acc[i][j] = (f32x4){0.f,0.f,0.f,0.f};

    const ushort_t* Ah_p[2]; const ushort_t* Al_p[2];
    const ushort_t* Bh_p[2]; const ushort_t* Bl_p[2];
    #pragma unroll
    for (int i = 0; i < 2; ++i) {
        size_t off = (size_t)(o0 + wy * 32 + i * 16 + ln) * 256 + quad * 8;
        Ah_p[i] = Wp_hi + off; Al_p[i] = Wp_lo + off;
    }
    #pragma unroll
    for (int j = 0; j < 2; ++j) {
        size_t off = ((size_t)(b * N_) + n0 + wx * 32 + j * 16 + ln) * 256 + quad * 8;
        Bh_p[j] = xs_hi + off; Bl_p[j] = xs_lo + off;
    }

    #pragma unroll 4
    for (int k0 = 0; k0 < 256; k0 += 32) {
        v8bf Ah[2], Al[2], Bh[2], Bl[2];
        #pragma unroll
        for (int i = 0; i < 2; ++i) { Ah[i] = ld8(Ah_p[i] + k0); Al[i] = ld8(Al_p[i] + k0); }
        #pragma unroll
        for (int j = 0; j < 2; ++j) { Bh[j] = ld8(Bh_p[j] + k0); Bl[j] = ld8(Bl_p[j] + k0); }
        #pragma unroll
        for (int i = 0; i < 2; ++i)
            #pragma unroll
            for (int j = 0; j < 2; ++j) {
                acc[i][j] = __builtin_amdgcn_mfma_f32_16x16x32_bf16(Ah[i], Bh[j], acc[i][j], 0, 0, 0);
                acc[i][j] = __builtin_amdgcn_mfma_f32_16x16x32_bf16(Ah[i], Bl[j], acc[i][j], 0, 0, 0);
                acc[i][j] = __builtin_amdgcn_mfma_f32_16x16x32_bf16(Al[i], Bh[j], acc[i][j], 0, 0, 0);
            }
    }

    if (o0 < 256) {
        // q or k: transposed store [n][o], pack 4 consecutive o (regs) into 8B
        ushort_t* th = (o0 < 128) ? qt_hi : kt_hi;
        ushort_t* tl = (o0 < 128) ? qt_lo : kt_lo;
        const int ob = o0 & 127;
        #pragma unroll
        for (int i = 0; i < 2; ++i)
            #pragma unroll
            for (int j = 0; j < 2; ++j) {
                int oo = ob + wy * 32 + i * 16 + quad * 4;
                int n  = n0 + wx * 32 + j * 16 + ln;
                unsigned int h01 = 0, h23 = 0, l01 = 0, l23 = 0;
                #pragma unroll
                for (int r = 0; r < 4; ++r) {
                    float f = acc[i][j][r];
                    unsigned short hh = f2bf_rne(f);
                    unsigned short lo = f2bf_rne(f - bf2f(hh));
                    if (r < 2) { h01 |= ((unsigned)hh) << (16 * r); l01 |= ((unsigned)lo) << (16 * r); }
                    else       { h23 |= ((unsigned)hh) << (16 * (r - 2)); l23 |= ((unsigned)lo) << (16 * (r - 2)); }
                }
                size_t off = ((size_t)(b * N_) + n) * 128 + oo;
                *(uint2*)&th[off] = make_uint2(h01, h23);
                *(uint2*)&tl[off] = make_uint2(l01, l23);
            }
    } else {
        // v: packed layout vB[b][m>>5][c][m&31]
        #pragma unroll
        for (int i = 0; i < 2; ++i)
            #pragma unroll
            for (int j = 0; j < 2; ++j)
                #pragma unroll
                for (int r = 0; r < 4; ++r) {
                    int c = (o0 - 256) + wy * 32 + i * 16 + quad * 4 + r;
                    int m = n0 + wx * 32 + j * 16 + ln;
                    float f = acc[i][j][r];
                    unsigned short hh = f2bf_rne(f);
                    unsigned short lo = f2bf_rne(f - bf2f(hh));
                    size_t off = (((size_t)b * 32 + (m >> 5)) * 128 + c) * 32 + (m & 31);
                    vB_hi[off] = hh; vB_lo[off] = lo;
                }
    }
}

// ---------------------------------------------------------------------------
// K2: fused attention: scores (3-term MFMA) + softmax + gate write + gv MFMA.
// Block = one 32-row n-strip of one batch. Waves partition m (256 each).
// Phase 1: S[32][1024] in registers (2 ntiles x 16 mtiles per wave).
// Phase 2: gv[c=128][n=32], B-frags from 64KB swizzled LDS bf16 gate tile.
__global__ __launch_bounds__(256, 1) void attn_fused_kernel(
    const ushort_t* __restrict__ qt_hi, const ushort_t* __restrict__ qt_lo,
    const ushort_t* __restrict__ kt_hi, const ushort_t* __restrict__ kt_lo,
    const ushort_t* __restrict__ vB_hi, const ushort_t* __restrict__ vB_lo,
    float* __restrict__ gate, float* __restrict__ gv)
{
    __shared__ __align__(16) char gsm[65536];     // Gbf[32][1024] bf16, 16B-chunk XOR swizzle
    __shared__ float redA[4][32];
    __shared__ float redB[4][32];

    const int n0 = blockIdx.x * 32;
    const int b  = blockIdx.y;
    const int tid = threadIdx.x;
    const int l = tid & 63, w = tid >> 6;
    const int ln = l & 15, quad = l >> 4;
    const int Mw = w * 256;

    const ushort_t* qb_h = qt_hi + ((size_t)(b * N_) + n0) * 128;
    const ushort_t* qb_l = qt_lo + ((size_t)(b * N_) + n0) * 128;
    const ushort_t* kb_h = kt_hi + (size_t)(b * N_) * 128;
    const ushort_t* kb_l = kt_lo + (size_t)(b * N_) * 128;

    f32x4 acc[2][16];
    #pragma unroll
    for (int nt = 0; nt < 2; ++nt)
        #pragma unroll
        for (int mt = 0; mt < 16; ++mt) acc[nt][mt] = (f32x4){0.f,0.f,0.f,0.f};

    // ---- phase 1: scores
    #pragma unroll
    for (int c0 = 0; c0 < 128; c0 += 32) {
        v8bf Ah[2], Al[2];
        #pragma unroll
        for (int nt = 0; nt < 2; ++nt) {
            size_t aoff = (size_t)(nt * 16 + ln) * 128 + c0 + quad * 8;
            Ah[nt] = ld8(qb_h + aoff); Al[nt] = ld8(qb_l + aoff);
        }
        #pragma unroll
        for (int mt = 0; mt < 16; ++mt) {
            size_t boff = (size_t)(Mw + mt * 16 + ln) * 128 + c0 + quad * 8;
            v8bf Bh = ld8(kb_h + boff);
            v8bf Bl = ld8(kb_l + boff);
            #pragma unroll
            for (int nt = 0; nt < 2; ++nt) {
                acc[nt][mt] = __builtin_amdgcn_mfma_f32_16x16x32_bf16(Ah[nt], Bh, acc[nt][mt], 0, 0, 0);
                acc[nt][mt] = __builtin_amdgcn_mfma_f32_16x16x32_bf16(Ah[nt], Bl, acc[nt][mt], 0, 0, 0);
                acc[nt][mt] = __builtin_amdgcn_mfma_f32_16x16x32_bf16(Al[nt], Bh, acc[nt][mt], 0, 0, 0);
            }
        }
    }

    // ---- softmax: row = n (C-layout row = quad*4+r per ntile), col = m = Mw+mt*16+ln
    float rmax[2][4];
    #pragma unroll
    for (int nt = 0; nt < 2; ++nt)
        #pragma unroll
        for (int r = 0; r < 4; ++r) {
            float m = acc[nt][0][r];
            #pragma unroll
            for (int mt = 1; mt < 16; ++mt) m = fmaxf(m, acc[nt][mt][r]);
            rmax[nt][r] = m;
        }
    #pragma unroll
    for (int nt = 0; nt < 2; ++nt)
        #pragma unroll
        for (int r = 0; r < 4; ++r) {
            float m = rmax[nt][r];
            #pragma unroll
            for (int xm = 1; xm <= 8; xm <<= 1) m = fmaxf(m, __shfl_xor(m, xm, 64));
            rmax[nt][r] = m;
        }
    if (ln == 0) {
        #pragma unroll
        for (int nt = 0; nt < 2; ++nt)
            #pragma unroll
            for (int r = 0; r < 4; ++r)
                redA[w][nt * 16 + quad * 4 + r] = rmax[nt][r];
    }
    __syncthreads();
    #pragma unroll
    for (int nt = 0; nt < 2; ++nt)
        #pragma unroll
        for (int r = 0; r < 4; ++r) {
            int row = nt * 16 + quad * 4 + r;
            rmax[nt][r] = fmaxf(fmaxf(redA[0][row], redA[1][row]),
                                fmaxf(redA[2][row], redA[3][row]));
        }

    float rsum[2][4];
    #pragma unroll
    for (int nt = 0; nt < 2; ++nt)
        #pragma unroll
        for (int r = 0; r < 4; ++r) {
            float s = 0.f;
            #pragma unroll
            for (int mt = 0; mt < 16; ++mt) {
                float e = __expf(acc[nt][mt][r] - rmax[nt][r]);
                acc[nt][mt][r] = e;
                s += e;
            }
            rsum[nt][r] = s;
        }
    #pragma unroll
    for (int nt = 0; nt < 2; ++nt)
        #pragma unroll
        for (int r = 0; r < 4; ++r) {
            float s = rsum[nt][r];
            #pragma unroll
            for (int xm = 1; xm <= 8; xm <<= 1) s += __shfl_xor(s, xm, 64);
            rsum[nt][r] = s;
        }
    if (ln == 0) {
        #pragma unroll
        for (int nt = 0; nt < 2; ++nt)
            #pragma unroll
            for (int r = 0; r < 4; ++r)
                redB[w][nt * 16 + quad * 4 + r] = rsum[nt][r];
    }
    __syncthreads();
    #pragma unroll
    for (int nt = 0; nt < 2; ++nt)
        #pragma unroll
        for (int r = 0; r < 4; ++r) {
            int row = nt * 16 + quad * 4 + r;
            float inv = 1.0f / (redB[0][row] + redB[1][row] + redB[2][row] + redB[3][row]);
            #pragma unroll
            for (int mt = 0; mt < 16; ++mt) acc[nt][mt][r] *= inv;
        }

    // ---- write gate fp32 + bf16 -> swizzled LDS
    float* grow = gate + (size_t)b * N_ * N_;
    #pragma unroll
    for (int nt = 0; nt < 2; ++nt)
        #pragma unroll
        for (int r = 0; r < 4; ++r) {
            int n  = n0 + nt * 16 + quad * 4 + r;
            int nl = nt * 16 + quad * 4 + r;
            #pragma unroll
            for (int mt = 0; mt < 16; ++mt) {
                int m = Mw + mt * 16 + ln;
                float v = acc[nt][mt][r];
                grow[(size_t)n * N_ + m] = v;
                int chunk = m >> 3;
                int addr = nl * 2048 + (((chunk ^ (nl & 7))) << 4) + ((m & 7) << 1);
                *(ushort_t*)&gsm[addr] = f2bf_rne(v);
            }
        }
    __syncthreads();

    // ---- phase 2: gv[c][n] = sum_m gate[n][m]*v[c][m], A = vB hi/lo, B from LDS
    const ushort_t* vb_h = vB_hi + (size_t)b * CI_ * N_;
    const ushort_t* vb_l = vB_lo + (size_t)b * CI_ * N_;

    f32x4 acc2[2][2];
    #pragma unroll
    for (int ct = 0; ct < 2; ++ct)
        #pragma unroll
        for (int nt = 0; nt < 2; ++nt) acc2[ct][nt] = (f32x4){0.f,0.f,0.f,0.f};

    #pragma unroll 4
    for (int m0 = 0; m0 < 1024; m0 += 32) {
        v8bf Bg[2];
        #pragma unroll
        for (int nt = 0; nt < 2; ++nt) {
            int nl = nt * 16 + ln;
            int chunk = (m0 >> 3) + quad;
            Bg[nt] = *(const v8bf*)&gsm[nl * 2048 + (((chunk ^ (nl & 7))) << 4)];
        }
        #pragma unroll
        for (int ct = 0; ct < 2; ++ct) {
            int c = w * 32 + ct * 16 + ln;
            size_t aoff = (((size_t)(m0 >> 5)) * 128 + c) * 32 + quad * 8;
            v8bf Avh = ld8(vb_h + aoff);
            v8bf Avl = ld8(vb_l + aoff);
            #pragma unroll
            for (int nt = 0; nt < 2; ++nt) {
                acc2[ct][nt] = __builtin_amdgcn_mfma_f32_16x16x32_bf16(Avh, Bg[nt], acc2[ct][nt], 0, 0, 0);
                acc2[ct][nt] = __builtin_amdgcn_mfma_f32_16x16x32_bf16(Avl, Bg[nt], acc2[ct][nt], 0, 0, 0);
            }
        }
    }

    #pragma unroll
    for (int ct = 0; ct < 2; ++ct)
        #pragma unroll
        for (int nt = 0; nt < 2; ++nt)
            #pragma unroll
            for (int r = 0; r < 4; ++r) {
                int c = w * 32 + ct * 16 + quad * 4 + r;
                int n = n0 + nt * 16 + ln;
                gv[(size_t)(b * CI_ + c) * N_ + n] = acc2[ct][nt][r];
            }
}

// ---------------------------------------------------------------------------
// K5: mean
__global__ __launch_bounds__(256) void mean_kernel(
    const float* __restrict__ gv, float* __restrict__ meanb)
{
    const int i = blockIdx.x, b = blockIdx.y;
    const int tid = threadIdx.x;
    const int wid = tid >> 6, lane = tid & 63;
    __shared__ float red[4];
    const float* base = gv + (size_t)(b * CI_ + i) * N_;
    float4 v = ((const float4*)base)[tid];
    float s = v.x + v.y + v.z + v.w;
    #pragma unroll
    for (int off = 32; off; off >>= 1) s += __shfl_xor(s, off, 64);
    if (lane == 0) red[wid] = s;
    __syncthreads();
    if (tid == 0)
        meanb[b * CI_ + i] = (red[0] + red[1] + red[2] + red[3]) * (1.0f / 1024.0f);
}

// ---------------------------------------------------------------------------
// K6: conv1d + sigmoid
__global__ __launch_bounds__(1024) void ca_kernel(
    const float* __restrict__ meanb, const float* __restrict__ w1d,
    float* __restrict__ ca)
{
    const int t = threadIdx.x;
    const int i = t & 127;
    float left  = (i > 0)   ? meanb[t - 1] : 0.0f;
    float mid   = meanb[t];
    float right = (i < 127) ? meanb[t + 1] : 0.0f;
    float val = w1d[0] * left + w1d[1] * mid + w1d[2] * right;
    ca[t] = 1.0f / (1.0f + __expf(-val));
}

// ---------------------------------------------------------------------------
// K7: MFMA conv (unchanged)
#define BHI 0
#define BLO 17408
#define AHI 34816
#define ALO 43008
__global__ __launch_bounds__(256) void conv_mfma_kernel(
    const float* __restrict__ gv, const float* __restrict__ ca,
    const ushort_t* __restrict__ Whi, const ushort_t* __restrict__ Wlo,
    float* __restrict__ out)
{
    __shared__ char smem[51200];
    const int b   = blockIdx.z;
    const int h0  = blockIdx.y * 2;
    const int o0  = blockIdx.x * 64;
    const int tid = threadIdx.x;
    const int l   = tid & 63;
    const int wv  = tid >> 6;
    const int wy  = wv >> 1;
    const int wx  = wv & 1;
    const int ln  = l & 15;
    const int quad = l >> 4;

    f32x4 acc[2][2];
    #pragma unroll
    for (int i = 0; i < 2; ++i)
        #pragma unroll
        for (int j = 0; j < 2; ++j)
            acc[i][j] = (f32x4){0.f, 0.f, 0.f, 0.f};

    for (int half = 0; half < 2; ++half) {
        __syncthreads();
        for (int u = tid; u < 136 * 16; u += 256) {
            int p   = u >> 4;
            int ciq = u & 15;
            int hrel = p / 34;
            int c    = p - hrel * 34;
            int gr = h0 + hrel - 1;
            int gc = c - 1;
            bool ok = ((unsigned)gr < 32u) && ((unsigned)gc < 32u);
            int cib = half * 64 + ciq * 4;
            unsigned int hx = 0, hy = 0, lx = 0, ly = 0;
            #pragma unroll
            for (int t = 0; t < 4; ++t) {
                float v = 0.0f;
                if (ok)
                    v = gv[(size_t)(b * CI_ + cib + t) * N_ + gr * 32 + gc]
                        * ca[b * CI_ + cib + t];
                unsigned short h = f2bf_rne(v);
                unsigned short lo = f2bf_rne(v - bf2f(h));
                if (t < 2) { hx |= ((unsigned)h) << (16 * t); lx |= ((unsigned)lo) << (16 * t); }
                else       { hy |= ((unsigned)h) << (16 * (t - 2)); ly |= ((unsigned)lo) << (16 * (t - 2)); }
            }
            int addr = p * 128 + (((ciq >> 1) ^ (p & 7)) << 4) + ((ciq & 1) << 3);
            *(uint2*)&smem[BHI + addr] = make_uint2(hx, hy);
            *(uint2*)&smem[BLO + addr] = make_uint2(lx, ly);
        }
        for (int tap = 0; tap < 9; ++tap) {
            __syncthreads();
            #pragma unroll
            for (int it = 0; it < 2; ++it) {
                int row = it * 32 + (tid >> 3);
                int s   = tid & 7;
                int csrc = s ^ (row & 7);
                size_t gsrc = (size_t)(o0 + row) * 1152 + tap * 128 + half * 64 + csrc * 8;
                int la = row * 128 + s * 16;
                *(uint4*)&smem[AHI + la] = *(const uint4*)&Whi[gsrc];
                *(uint4*)&smem[ALO + la] = *(const uint4*)&Wlo[gsrc];
            }
            __syncthreads();
            const int dy = tap / 3, dx = tap - dy * 3;
            const int pbase = (wx + dy) * 34 + dx;
            #pragma unroll
            for (int cc = 0; cc < 2; ++cc) {
                v8bf Bh[2], Bl[2], Ah[2], Al[2];
                #pragma unroll
                for (int j = 0; j < 2; ++j) {
                    int p = pbase + j * 16 + ln;
                    int ch = cc * 4 + quad;
                    int addr = p * 128 + ((ch ^ (p & 7)) << 4);
                    Bh[j] = *(const v8bf*)&smem[BHI + addr];
                    Bl[j] = *(const v8bf*)&smem[BLO + addr];
                }
                #pragma unroll
                for (int i = 0; i < 2; ++i) {
                    int o = wy * 32 + i * 16 + ln;
                    int ch = cc * 4 + quad;
                    int addr = o * 128 + ((ch ^ (o & 7)) << 4);
                    Ah[i] = *(const v8bf*)&smem[AHI + addr];
                    Al[i] = *(const v8bf*)&smem[ALO + addr];
                }
                #pragma unroll
                for (int i = 0; i < 2; ++i)
                    #pragma unroll
                    for (int j = 0; j < 2; ++j) {
                        acc[i][j] = __builtin_amdgcn_mfma_f32_16x16x32_bf16(Ah[i], Bh[j], acc[i][j], 0, 0, 0);
                        acc[i][j] = __builtin_amdgcn_mfma_f32_16x16x32_bf16(Ah[i], Bl[j], acc[i][j], 0, 0, 0);
                        acc[i][j] = __builtin_amdgcn_mfma_f32_16x16x32_bf16(Al[i], Bh[j], acc[i][j], 0, 0, 0);
                    }
            }
        }
    }

    const int h = h0 + wx;
    #pragma unroll
    for (int i = 0; i < 2; ++i)
        #pragma unroll
        for (int j = 0; j < 2; ++j)
            #pragma unroll
            for (int r = 0; r < 4; ++r) {
                int o = o0 + wy * 32 + i * 16 + quad * 4 + r;
                int w = j * 16 + ln;
                out[(size_t)(b * CO_ + o) * N_ + h * 32 + w] = acc[i][j][r];
            }
}

// ---------------------------------------------------------------------------
extern "C" void kernel_launch(void* const* d_in, const int* in_sizes, int n_in,
                              void* d_out, int out_size, void* d_ws, size_t ws_size,
                              hipStream_t stream) {
    const float* x   = (const float*)d_in[0];
    const float* Wq  = (const float*)d_in[1];
    const float* Wk  = (const float*)d_in[2];
    const float* Wv  = (const float*)d_in[3];
    const float* w1d = (const float*)d_in[4];
    const float* Wc  = (const float*)d_in[5];

    float* out  = (float*)d_out;
    float* gate = out + 2097152;
    float* ca   = gate + 8388608;

    float*    gv      = (float*)d_ws;            // 1048576 f
    float*    meanb   = gv + 1048576;            // 1024 f
    ushort_t* Whi     = (ushort_t*)(meanb + 1024);   // 294912
    ushort_t* Wlo     = Whi + 294912;
    ushort_t* Wp_hi   = Wlo + 294912;            // 98304
    ushort_t* Wp_lo   = Wp_hi + 98304;
    ushort_t* xs_hi   = Wp_lo + 98304;           // 2097152
    ushort_t* xs_lo   = xs_hi + 2097152;
    ushort_t* qt_hi   = xs_lo + 2097152;         // 1048576
    ushort_t* qt_lo   = qt_hi + 1048576;
    ushort_t* kt_hi   = qt_lo + 1048576;
    ushort_t* kt_lo   = kt_hi + 1048576;
    ushort_t* vB_hi   = kt_lo + 1048576;         // 1048576 (packed [b][m>>5][c][m&31])
    ushort_t* vB_lo   = vB_hi + 1048576;

    prep_w_kernel<<<dim3(1536), 256, 0, stream>>>(Wc, Wq, Wk, Wv, Whi, Wlo, Wp_hi, Wp_lo);
    prep_x_kernel<<<dim3(32, 8), 256, 0, stream>>>(x, xs_hi, xs_lo);
    proj_mfma_kernel<<<dim3(16, 6, 8), 256, 0, stream>>>(
        Wp_hi, Wp_lo, xs_hi, xs_lo, qt_hi, qt_lo, kt_hi, kt_lo, vB_hi, vB_lo);
    attn_fused_kernel<<<dim3(32, 8), 256, 0, stream>>>(
        qt_hi, qt_lo, kt_hi, kt_lo, vB_hi, vB_lo, gate, gv);
    mean_kernel<<<dim3(128, 8), 256, 0, stream>>>(gv, meanb);
    ca_kernel<<<1, 1024, 0, stream>>>(meanb, w1d, ca);
    conv_mfma_kernel<<<dim3(4, 16, 8), 256, 0, stream>>>(gv, ca, Whi, Wlo, out);
}